// Round 2
// baseline (286.183 us; speedup 1.0000x reference)
//
#include <hip/hip_runtime.h>

#define BATCH 2
#define SS    256   // 16x16 subdomain grid
#define CC    128
#define HWN   256   // 16x16 spatial
#define NHEAD 8
#define FDIM  4096  // 64 ch * 8 * 8 per head

typedef unsigned int uint;
typedef unsigned short ushort;
typedef short bf16x8 __attribute__((ext_vector_type(8)));
typedef ushort us4 __attribute__((ext_vector_type(4)));
typedef float f32x4 __attribute__((ext_vector_type(4)));

__device__ __forceinline__ ushort f2b(float f) {
  uint u = __float_as_uint(f);
  return (ushort)((u + 0x7fffu + ((u >> 16) & 1u)) >> 16);  // RNE
}
__device__ __forceinline__ float b2f(ushort h) { return __uint_as_float((uint)h << 16); }

// ---------------- K0: convert weights to bf16 ----------------
__global__ void k_convert(const float* __restrict__ wqkv, const float* __restrict__ wout,
                          ushort* __restrict__ wqkv_b, ushort* __restrict__ wout_b) {
  int i = blockIdx.x * 256 + threadIdx.x;
  if (i < 384 * 128) wqkv_b[i] = f2b(wqkv[i]);
  if (i < 128 * 128) wout_b[i] = f2b(wout[i]);
}

// ---------------- K1: qkv projection + head scatter ----------------
// Grid: 512 (b,s) x 3 (qkvi). Per block: GEMM [128 x 128] @ [128 x 256].
// Unified layout for q,k,v: qkvh[(qkvi*16 + b*8 + n)][s][f], f = hwl*64 + c.
__global__ __launch_bounds__(256) void k_qkv(const float* __restrict__ seq,
                                             const ushort* __restrict__ wqkv_b,
                                             ushort* __restrict__ qkvh) {
  const int blk = blockIdx.x;
  const int bs = blk / 3, qkvi = blk - bs * 3;
  const int b = bs >> 8, s = bs & 255;
  const int t = threadIdx.x;
  const int wave = t >> 6, lane = t & 63;
  const int qq = lane >> 4, m = lane & 15;

  const float* sp = seq + (size_t)bs * (CC * HWN);

  // B fragments: bfrag[ntp][ks] elem j = bf16(seq[k=ks*32+qq*8+j][hw=(wave*4+ntp)*16+m])
  bf16x8 bfrag[4][4];
  #pragma unroll
  for (int ntp = 0; ntp < 4; ++ntp) {
    const int hw = (wave * 4 + ntp) * 16 + m;
    #pragma unroll
    for (int ks = 0; ks < 4; ++ks) {
      const int k0 = ks * 32 + qq * 8;
      float tmp[8];
      #pragma unroll
      for (int j = 0; j < 8; ++j) tmp[j] = sp[(k0 + j) * HWN + hw];
      bf16x8 fr;
      #pragma unroll
      for (int j = 0; j < 8; ++j) fr[j] = (short)f2b(tmp[j]);
      bfrag[ntp][ks] = fr;
    }
  }

  #pragma unroll
  for (int mt8 = 0; mt8 < 8; ++mt8) {
    const int mt = qkvi * 8 + mt8;
    bf16x8 afrag[4];
    const ushort* ap = wqkv_b + (mt * 16 + m) * CC;
    #pragma unroll
    for (int ks = 0; ks < 4; ++ks) afrag[ks] = *(const bf16x8*)(ap + ks * 32 + qq * 8);
    const int ch = (mt8 >> 2) & 1;    // channel head
    #pragma unroll
    for (int ntp = 0; ntp < 4; ++ntp) {
      f32x4 acc = {0.f, 0.f, 0.f, 0.f};
      #pragma unroll
      for (int ks = 0; ks < 4; ++ks)
        acc = __builtin_amdgcn_mfma_f32_16x16x32_bf16(afrag[ks], bfrag[ntp][ks], acc, 0, 0, 0);
      const int ntg = wave * 4 + ntp;                       // == hy (hw row)
      const int n   = ((ntg >> 3) * 2 + (m >> 3)) * 2 + ch; // head
      const int hwl = (ntg & 7) * 8 + (m & 7);              // local spatial idx
      const int c   = (mt8 & 3) * 16 + qq * 4;              // channel within head
      const size_t base = ((size_t)(qkvi * 16 + b * 8 + n) * SS + s) * FDIM;
      us4 pk;
      #pragma unroll
      for (int r = 0; r < 4; ++r) pk[r] = f2b(acc[r]);
      *(us4*)(qkvh + base + hwl * 64 + c) = pk;
    }
  }
}

// ---------------- K2: masked scores + softmax -> 9 weights per (b,n,s) --------
__global__ __launch_bounds__(256) void k_scores(const ushort* __restrict__ qkvh,
                                                float* __restrict__ attn) {
  const int wid = blockIdx.x * 4 + (threadIdx.x >> 6);
  const int lane = threadIdx.x & 63;
  const int b = wid >> 11;
  const int n = (wid >> 8) & 7;
  const int s = wid & 255;
  const int sy = s >> 4, sx = s & 15;
  const size_t hs = (size_t)SS * FDIM;

  const ushort* qp = qkvh + (size_t)(b * 8 + n) * hs + (size_t)s * FDIM + lane * 8;
  bf16x8 qf[8];
  #pragma unroll
  for (int i = 0; i < 8; ++i) qf[i] = *(const bf16x8*)(qp + i * 512);

  float sc[9];
  #pragma unroll
  for (int j = 0; j < 9; ++j) {
    const int dy = j / 3 - 1, dx = j % 3 - 1;
    const int ny = sy + dy, nx = sx + dx;
    const bool valid = (ny >= 0 && ny < 16 && nx >= 0 && nx < 16);
    const int sj = valid ? (ny * 16 + nx) : s;
    const ushort* kp = qkvh + (size_t)(16 + b * 8 + n) * hs + (size_t)sj * FDIM + lane * 8;
    float acc = 0.f;
    #pragma unroll
    for (int i = 0; i < 8; ++i) {
      bf16x8 kf = *(const bf16x8*)(kp + i * 512);
      #pragma unroll
      for (int e = 0; e < 8; ++e) acc += b2f((ushort)qf[i][e]) * b2f((ushort)kf[e]);
    }
    #pragma unroll
    for (int off = 32; off > 0; off >>= 1) acc += __shfl_xor(acc, off);
    sc[j] = valid ? acc * (1.f / 64.f) : -1e30f;
  }
  float mx = sc[0];
  #pragma unroll
  for (int j = 1; j < 9; ++j) mx = fmaxf(mx, sc[j]);
  float sum = 0.f, p[9];
  #pragma unroll
  for (int j = 0; j < 9; ++j) { p[j] = __expf(sc[j] - mx); sum += p[j]; }
  const float inv = 1.f / sum;
  if (lane < 9) {
    float v = p[0];
    #pragma unroll
    for (int j = 1; j < 9; ++j) v = (lane == j) ? p[j] : v;
    attn[((size_t)(b * 8 + n) * SS + s) * 9 + lane] = v * inv;
  }
}

// ---------------- K3: PV (in B-fragment layout) + out projection --------------
// Grid: 512 (b,s) x 4 (sub). Wave w handles single ntg = sub*4 + w.
__global__ __launch_bounds__(256) void k_out(const ushort* __restrict__ qkvh,
                                             const float* __restrict__ attn,
                                             const ushort* __restrict__ wout_b,
                                             const float* __restrict__ bout,
                                             float* __restrict__ out) {
  const int blk = blockIdx.x;
  const int bs = blk >> 2, sub = blk & 3;
  const int b = bs >> 8, s = bs & 255;
  const int t = threadIdx.x;
  const int wave = t >> 6, lane = t & 63;
  const int ntg = sub * 4 + wave;        // hw row / 16
  const int qq = lane >> 4, m = lane & 15;
  const int sy = s >> 4, sx = s & 15;
  const size_t hs = (size_t)SS * FDIM;

  int sjc[9];
  #pragma unroll
  for (int j = 0; j < 9; ++j) {
    const int ny = min(max(sy + j / 3 - 1, 0), 15);
    const int nx = min(max(sx + j % 3 - 1, 0), 15);
    sjc[j] = ny * 16 + nx;
  }

  const int yh = ntg >> 3;
  const int nbase = (yh * 2 + (m >> 3)) * 2;  // + ch
  float pch[2][9];
  #pragma unroll
  for (int ch = 0; ch < 2; ++ch) {
    #pragma unroll
    for (int j = 0; j < 9; ++j)
      pch[ch][j] = attn[((size_t)(b * 8 + nbase + ch) * SS + s) * 9 + j];
  }

  // sa in MFMA B-fragment layout: B[cc=ks*32+qq*8+j][hw=ntg*16+m]
  const int hwl = (ntg & 7) * 8 + (m & 7);
  bf16x8 bfrag[4];
  #pragma unroll
  for (int ks = 0; ks < 4; ++ks) {
    const int ch = ks >> 1;
    const int c0 = (ks * 32 + qq * 8) & 63;
    const ushort* vb = qkvh + (size_t)(32 + b * 8 + nbase + ch) * hs;
    float facc[8] = {0.f, 0.f, 0.f, 0.f, 0.f, 0.f, 0.f, 0.f};
    #pragma unroll
    for (int j = 0; j < 9; ++j) {
      bf16x8 vv = *(const bf16x8*)(vb + (size_t)sjc[j] * FDIM + hwl * 64 + c0);
      const float pj = pch[ch][j];
      #pragma unroll
      for (int e = 0; e < 8; ++e) facc[e] += pj * b2f((ushort)vv[e]);
    }
    bf16x8 fr;
    #pragma unroll
    for (int e = 0; e < 8; ++e) fr[e] = (short)f2b(facc[e]);
    bfrag[ks] = fr;
  }

  // out[d][hw] = wout[d][cc] @ sa[cc][hw] + bout[d]
  #pragma unroll
  for (int mt = 0; mt < 8; ++mt) {
    bf16x8 afrag[4];
    const ushort* ap = wout_b + (mt * 16 + m) * CC;
    #pragma unroll
    for (int ks = 0; ks < 4; ++ks) afrag[ks] = *(const bf16x8*)(ap + ks * 32 + qq * 8);
    f32x4 acc = {0.f, 0.f, 0.f, 0.f};
    #pragma unroll
    for (int ks = 0; ks < 4; ++ks)
      acc = __builtin_amdgcn_mfma_f32_16x16x32_bf16(afrag[ks], bfrag[ks], acc, 0, 0, 0);
    const int hw = ntg * 16 + m;
    #pragma unroll
    for (int r = 0; r < 4; ++r) {
      const int d = mt * 16 + qq * 4 + r;
      out[((size_t)bs * CC + d) * HWN + hw] = acc[r] + bout[d];
    }
  }
}

extern "C" void kernel_launch(void* const* d_in, const int* in_sizes, int n_in,
                              void* d_out, int out_size, void* d_ws, size_t ws_size,
                              hipStream_t stream) {
  const float* seq  = (const float*)d_in[0];
  const float* wqkv = (const float*)d_in[1];
  const float* wout = (const float*)d_in[2];
  const float* bout = (const float*)d_in[3];
  char* ws = (char*)d_ws;
  // ws layout (bytes): wqkv_b 98304 | wout_b 32768 | qkvh 100663296 | attn 147456
  ushort* wqkv_b = (ushort*)(ws);
  ushort* wout_b = (ushort*)(ws + 98304);
  ushort* qkvh   = (ushort*)(ws + 131072);
  float*  attn   = (float*)(ws + 131072 + 100663296ull);
  float*  outp   = (float*)d_out;

  hipLaunchKernelGGL(k_convert, dim3(192),  dim3(256), 0, stream, wqkv, wout, wqkv_b, wout_b);
  hipLaunchKernelGGL(k_qkv,     dim3(1536), dim3(256), 0, stream, seq, wqkv_b, qkvh);
  hipLaunchKernelGGL(k_scores,  dim3(1024), dim3(256), 0, stream, qkvh, attn);
  hipLaunchKernelGGL(k_out,     dim3(2048), dim3(256), 0, stream, qkvh, attn, wout_b, bout, outp);
}

// Round 3
// 265.797 us; speedup vs baseline: 1.0767x; 1.0767x over previous
//
#include <hip/hip_runtime.h>

#define BATCH 2
#define SS    256   // 16x16 subdomain grid
#define CC    128
#define HWN   256   // 16x16 spatial
#define NHEAD 8
#define FDIM  4096  // 64 ch * 8 * 8 per head

typedef unsigned int uint;
typedef unsigned short ushort;
typedef short bf16x8 __attribute__((ext_vector_type(8)));
typedef ushort us4 __attribute__((ext_vector_type(4)));
typedef float f32x4 __attribute__((ext_vector_type(4)));

__device__ __forceinline__ ushort f2b(float f) {
  uint u = __float_as_uint(f);
  return (ushort)((u + 0x7fffu + ((u >> 16) & 1u)) >> 16);  // RNE
}
__device__ __forceinline__ float b2f(ushort h) { return __uint_as_float((uint)h << 16); }

// ---------------- K0: convert weights to bf16 ----------------
__global__ void k_convert(const float* __restrict__ wqkv, const float* __restrict__ wout,
                          ushort* __restrict__ wqkv_b, ushort* __restrict__ wout_b) {
  int i = blockIdx.x * 256 + threadIdx.x;
  if (i < 384 * 128) wqkv_b[i] = f2b(wqkv[i]);
  if (i < 128 * 128) wout_b[i] = f2b(wout[i]);
}

// ---------------- K1: qkv projection + head scatter ----------------
// Grid: 512 bs x 4 hw-quarters, 128 threads. seq read exactly once.
// q,k layout: qkvh[(qkvi*16+b*8+n)][s][f], f = hwl*64 + c
// v   layout: f_v = (c>>5)*2048 + hwl*32 + ((c>>3)&3)*8 + (c&7)   (dense for k_out)
__global__ __launch_bounds__(128) void k_qkv(const float* __restrict__ seq,
                                             const ushort* __restrict__ wqkv_b,
                                             ushort* __restrict__ qkvh) {
  const int blk = blockIdx.x;
  const int bs = blk >> 2, hq = blk & 3;
  const int b = bs >> 8, s = bs & 255;
  const int t = threadIdx.x;
  const int wave = t >> 6, lane = t & 63;
  const int qq = lane >> 4, m = lane & 15;

  const float* sp = seq + (size_t)bs * (CC * HWN);

  // B fragments for this block's 32 hw per wave (2 ntg of 16)
  bf16x8 bfrag[2][4];
  #pragma unroll
  for (int ntp = 0; ntp < 2; ++ntp) {
    const int ntg = hq * 4 + wave * 2 + ntp;
    const int hw = ntg * 16 + m;
    #pragma unroll
    for (int ks = 0; ks < 4; ++ks) {
      const int k0 = ks * 32 + qq * 8;
      float tmp[8];
      #pragma unroll
      for (int j = 0; j < 8; ++j) tmp[j] = sp[(k0 + j) * HWN + hw];
      bf16x8 fr;
      #pragma unroll
      for (int j = 0; j < 8; ++j) fr[j] = (short)f2b(tmp[j]);
      bfrag[ntp][ks] = fr;
    }
  }

  for (int mt = 0; mt < 24; ++mt) {
    bf16x8 afrag[4];
    const ushort* ap = wqkv_b + (mt * 16 + m) * CC;
    #pragma unroll
    for (int ks = 0; ks < 4; ++ks) afrag[ks] = *(const bf16x8*)(ap + ks * 32 + qq * 8);
    const int qkvi = mt >> 3, mt8 = mt & 7;
    const int ch = (mt8 >> 2) & 1;     // channel head
    const int m4 = mt8 & 3;
    #pragma unroll
    for (int ntp = 0; ntp < 2; ++ntp) {
      f32x4 acc = {0.f, 0.f, 0.f, 0.f};
      #pragma unroll
      for (int ks = 0; ks < 4; ++ks)
        acc = __builtin_amdgcn_mfma_f32_16x16x32_bf16(afrag[ks], bfrag[ntp][ks], acc, 0, 0, 0);
      const int ntg = hq * 4 + wave * 2 + ntp;              // hw row
      const int n   = ((ntg >> 3) * 2 + (m >> 3)) * 2 + ch; // head
      const int hwl = (ntg & 7) * 8 + (m & 7);              // local spatial idx
      const size_t base = ((size_t)(qkvi * 16 + b * 8 + n) * SS + s) * FDIM;
      us4 pk;
      #pragma unroll
      for (int r = 0; r < 4; ++r) pk[r] = f2b(acc[r]);
      if (qkvi < 2) {
        *(us4*)(qkvh + base + hwl * 64 + m4 * 16 + qq * 4) = pk;
      } else {
        const int fv = (m4 >> 1) * 2048 + hwl * 32 + ((m4 & 1) * 2 + (qq >> 1)) * 8 + (qq & 1) * 4;
        *(us4*)(qkvh + base + fv) = pk;
      }
    }
  }
}

// ---------------- K2: MFMA scores + softmax -> <=9 weights per (b,n,s) -------
// Block = one (b,n,sy) unit; 4 waves split K (f-dim) into 1024-chunks; LDS reduce.
// Scores tile: 16 s (row sy) x 48 t (rows sy-1..sy+1).
__global__ __launch_bounds__(256) void k_scores(const ushort* __restrict__ qkvh,
                                                float* __restrict__ attn) {
  const int unit = blockIdx.x;            // (b,n,sy)
  const int b  = unit >> 7;
  const int n  = (unit >> 4) & 7;
  const int sy = unit & 15;
  const int t = threadIdx.x;
  const int wave = t >> 6, lane = t & 63;
  const int qq = lane >> 4, l15 = lane & 15;
  const size_t hs = (size_t)SS * FDIM;
  const ushort* qb = qkvh + (size_t)(b * 8 + n) * hs;
  const ushort* kb = qkvh + (size_t)(16 + b * 8 + n) * hs;

  const ushort* qp = qb + (size_t)(sy * 16 + l15) * FDIM + qq * 8;
  const ushort* kp[3];
  #pragma unroll
  for (int tl = 0; tl < 3; ++tl) {
    const int tyc = min(max(sy - 1 + tl, 0), 15);
    kp[tl] = kb + (size_t)(tyc * 16 + l15) * FDIM + qq * 8;
  }

  f32x4 acc[3] = {{0,0,0,0},{0,0,0,0},{0,0,0,0}};
  const int kbeg = wave * 1024, kend = kbeg + 1024;
  for (int k0 = kbeg; k0 < kend; k0 += 32) {
    bf16x8 af = *(const bf16x8*)(qp + k0);
    #pragma unroll
    for (int tl = 0; tl < 3; ++tl) {
      bf16x8 bf = *(const bf16x8*)(kp[tl] + k0);
      acc[tl] = __builtin_amdgcn_mfma_f32_16x16x32_bf16(af, bf, acc[tl], 0, 0, 0);
    }
  }

  // cross-wave reduce: waves 1..3 dump partials, wave 0 sums
  __shared__ float red[3][64][12];   // [wave-1][lane][tl*4+r]
  if (wave > 0) {
    #pragma unroll
    for (int tl = 0; tl < 3; ++tl)
      #pragma unroll
      for (int r = 0; r < 4; ++r) red[wave - 1][lane][tl * 4 + r] = acc[tl][r];
  }
  __syncthreads();
  if (wave != 0) return;
  #pragma unroll
  for (int w = 0; w < 3; ++w)
    #pragma unroll
    for (int tl = 0; tl < 3; ++tl)
      #pragma unroll
      for (int r = 0; r < 4; ++r) acc[tl][r] += red[w][lane][tl * 4 + r];

  // mask + softmax.  D layout: row(s-in-row sx) = qq*4+r, col(tx) = l15.
  const int tx = l15;
  float sc[3][4];
  #pragma unroll
  for (int tl = 0; tl < 3; ++tl) {
    const int ty = sy - 1 + tl;
    const bool tyv = (ty >= 0 && ty < 16);
    #pragma unroll
    for (int r = 0; r < 4; ++r) {
      const int sx = qq * 4 + r;
      const bool v = tyv && (tx - sx <= 1) && (sx - tx <= 1);
      sc[tl][r] = v ? acc[tl][r] * (1.f / 64.f) : -1e30f;
    }
  }
  #pragma unroll
  for (int r = 0; r < 4; ++r) {
    float mx = fmaxf(fmaxf(sc[0][r], sc[1][r]), sc[2][r]);
    #pragma unroll
    for (int off = 1; off < 16; off <<= 1) mx = fmaxf(mx, __shfl_xor(mx, off));
    float p[3], sum = 0.f;
    #pragma unroll
    for (int tl = 0; tl < 3; ++tl) { p[tl] = __expf(sc[tl][r] - mx); sum += p[tl]; }
    #pragma unroll
    for (int off = 1; off < 16; off <<= 1) sum += __shfl_xor(sum, off);
    const float inv = 1.f / sum;
    const int sx = qq * 4 + r;
    const int s = sy * 16 + sx;
    #pragma unroll
    for (int tl = 0; tl < 3; ++tl) {
      const int ty = sy - 1 + tl;
      const int dxp = tx - sx + 1;
      if (ty >= 0 && ty < 16 && dxp >= 0 && dxp <= 2)
        attn[((size_t)(b * 8 + n) * SS + s) * 9 + tl * 3 + dxp] = p[tl] * inv;
    }
  }
}

// ---------------- K3: PV (dense v loads) + out projection --------------------
// Grid: 512 bs x 4 sub; wave handles ntg = sub*4 + wave.
__global__ __launch_bounds__(256) void k_out(const ushort* __restrict__ qkvh,
                                             const float* __restrict__ attn,
                                             const ushort* __restrict__ wout_b,
                                             const float* __restrict__ bout,
                                             float* __restrict__ out) {
  const int blk = blockIdx.x;
  const int bs = blk >> 2, sub = blk & 3;
  const int b = bs >> 8, s = bs & 255;
  const int t = threadIdx.x;
  const int wave = t >> 6, lane = t & 63;
  const int ntg = sub * 4 + wave;
  const int qq = lane >> 4, m = lane & 15;
  const int sy = s >> 4, sx = s & 15;
  const size_t hs = (size_t)SS * FDIM;

  int sjc[9];
  bool vld[9];
  #pragma unroll
  for (int j = 0; j < 9; ++j) {
    const int ny = sy + j / 3 - 1, nx = sx + j % 3 - 1;
    vld[j] = (ny >= 0 && ny < 16 && nx >= 0 && nx < 16);
    sjc[j] = min(max(ny, 0), 15) * 16 + min(max(nx, 0), 15);
  }

  const int yh = ntg >> 3;
  const int nbase = (yh * 2 + (m >> 3)) * 2;  // + ch
  float pch[2][9];
  #pragma unroll
  for (int ch = 0; ch < 2; ++ch) {
    #pragma unroll
    for (int j = 0; j < 9; ++j) {
      const float w = attn[((size_t)(b * 8 + nbase + ch) * SS + s) * 9 + j];
      pch[ch][j] = vld[j] ? w : 0.f;
    }
  }

  // sa in MFMA B-fragment layout via dense v layout
  const int hwl = (ntg & 7) * 8 + (m & 7);
  bf16x8 bfrag[4];
  #pragma unroll
  for (int ks = 0; ks < 4; ++ks) {
    const int ch = ks >> 1;
    const ushort* vb = qkvh + (size_t)(32 + b * 8 + nbase + ch) * hs;
    const int fv = (ks & 1) * 2048 + hwl * 32 + qq * 8;
    float facc[8] = {0.f, 0.f, 0.f, 0.f, 0.f, 0.f, 0.f, 0.f};
    #pragma unroll
    for (int j = 0; j < 9; ++j) {
      bf16x8 vv = *(const bf16x8*)(vb + (size_t)sjc[j] * FDIM + fv);
      const float pj = pch[ch][j];
      #pragma unroll
      for (int e = 0; e < 8; ++e) facc[e] += pj * b2f((ushort)vv[e]);
    }
    bf16x8 fr;
    #pragma unroll
    for (int e = 0; e < 8; ++e) fr[e] = (short)f2b(facc[e]);
    bfrag[ks] = fr;
  }

  // out[d][hw] = wout[d][cc] @ sa[cc][hw] + bout[d]
  #pragma unroll
  for (int mt = 0; mt < 8; ++mt) {
    bf16x8 afrag[4];
    const ushort* ap = wout_b + (mt * 16 + m) * CC;
    #pragma unroll
    for (int ks = 0; ks < 4; ++ks) afrag[ks] = *(const bf16x8*)(ap + ks * 32 + qq * 8);
    f32x4 acc = {0.f, 0.f, 0.f, 0.f};
    #pragma unroll
    for (int ks = 0; ks < 4; ++ks)
      acc = __builtin_amdgcn_mfma_f32_16x16x32_bf16(afrag[ks], bfrag[ks], acc, 0, 0, 0);
    const int hw = ntg * 16 + m;
    #pragma unroll
    for (int r = 0; r < 4; ++r) {
      const int d = mt * 16 + qq * 4 + r;
      out[((size_t)bs * CC + d) * HWN + hw] = acc[r] + bout[d];
    }
  }
}

extern "C" void kernel_launch(void* const* d_in, const int* in_sizes, int n_in,
                              void* d_out, int out_size, void* d_ws, size_t ws_size,
                              hipStream_t stream) {
  const float* seq  = (const float*)d_in[0];
  const float* wqkv = (const float*)d_in[1];
  const float* wout = (const float*)d_in[2];
  const float* bout = (const float*)d_in[3];
  char* ws = (char*)d_ws;
  // ws layout (bytes): wqkv_b 98304 | wout_b 32768 | qkvh 100663296 | attn 147456
  ushort* wqkv_b = (ushort*)(ws);
  ushort* wout_b = (ushort*)(ws + 98304);
  ushort* qkvh   = (ushort*)(ws + 131072);
  float*  attn   = (float*)(ws + 131072 + 100663296ull);
  float*  outp   = (float*)d_out;

  hipLaunchKernelGGL(k_convert, dim3(192),  dim3(256), 0, stream, wqkv, wout, wqkv_b, wout_b);
  hipLaunchKernelGGL(k_qkv,     dim3(2048), dim3(128), 0, stream, seq, wqkv_b, qkvh);
  hipLaunchKernelGGL(k_scores,  dim3(256),  dim3(256), 0, stream, qkvh, attn);
  hipLaunchKernelGGL(k_out,     dim3(2048), dim3(256), 0, stream, qkvh, attn, wout_b, bout, outp);
}